// Round 1
// baseline (1176.185 us; speedup 1.0000x reference)
//
#include <hip/hip_runtime.h>

#define NN 100000      // nodes
#define EE 600000      // edges per etype
#define F  128         // IN == H == 128
#define NF (NN * F)
#define SLOT_CAP 64

// ---------------- degree counting (out-degree over src, all 3 etypes) ------
__global__ void count_out_kernel(const int* __restrict__ src0,
                                 const int* __restrict__ src1,
                                 const int* __restrict__ src2,
                                 int* __restrict__ out_cnt) {
    int i = blockIdx.x * blockDim.x + threadIdx.x;
    if (i >= EE) return;
    int e = blockIdx.y;
    const int* s = (e == 0) ? src0 : (e == 1) ? src1 : src2;
    atomicAdd(&out_cnt[e * NN + s[i]], 1);
}

__global__ void rs_out_kernel(const int* __restrict__ cnt, float* __restrict__ rs) {
    int i = blockIdx.x * blockDim.x + threadIdx.x;
    if (i >= 3 * NN) return;
    int c = cnt[i];
    if (c < 1) c = 1;
    rs[i] = rsqrtf((float)c);
}

// ---------------- bucket edges by dst (builds per-node src list) -----------
__global__ void fill_kernel(const int* __restrict__ src, const int* __restrict__ dst,
                            int* __restrict__ in_cnt, int* __restrict__ slots) {
    int i = blockIdx.x * blockDim.x + threadIdx.x;
    if (i >= EE) return;
    int d = dst[i];
    int p = atomicAdd(&in_cnt[d], 1);
    if (p < SLOT_CAP) slots[d * SLOT_CAP + p] = src[i];
}

// ---------------- atomic-free gather SpMM with both norms ------------------
// agg[d] = rsqrt(in_deg[d]) * sum_{s in N(d)} feat[s] * rsqrt(out_deg[s])
__global__ __launch_bounds__(256) void gather_kernel(
        const float* __restrict__ feat,
        const int* __restrict__ slots,
        const int* __restrict__ in_cnt,
        const float* __restrict__ rs_out,
        float* __restrict__ agg) {
    int node = blockIdx.x * 2 + (threadIdx.x >> 7);
    int c = threadIdx.x & 127;
    if (node >= NN) return;
    int cnt = in_cnt[node];
    int lim = cnt < SLOT_CAP ? cnt : SLOT_CAP;
    float acc = 0.f;
    for (int j = 0; j < lim; ++j) {
        int s = slots[node * SLOT_CAP + j];
        acc += feat[s * F + c] * rs_out[s];
    }
    float rin = rsqrtf((float)(cnt < 1 ? 1 : cnt));
    agg[node * F + c] = acc * rin;
}

// ---------------- fp32 matmul: C[r] = act(A[r] @ W + bias), K=F, cols=F ----
// 32 rows / block, 256 threads: tr=tid>>5 (4 rows each), tc=tid&31 (4 cols).
// A staged once in LDS (row-major, pad 132 keeps float4 16B-aligned and
// conflict-free staging); W staged in 32-k chunks (16KB). 33KB LDS -> 4 blk/CU.
// In-place safe (A fully staged before any store).
__global__ __launch_bounds__(256) void matmul_kernel(
        const float* __restrict__ A, const float* __restrict__ W,
        const float* __restrict__ bias, float* __restrict__ C, int relu_flag) {
    __shared__ __align__(16) float As[32][132];
    __shared__ __align__(16) float Ws[32 * 128];
    int tid = threadIdx.x;
    int row0 = blockIdx.x * 32;

    // stage A rows: coalesced float4 global reads
    for (int i = tid; i < 32 * 32; i += 256) {
        int r = i >> 5, kq = (i & 31) * 4;
        float4 v = *(const float4*)&A[(row0 + r) * F + kq];
        *(float4*)&As[r][kq] = v;
    }

    int tr = tid >> 5;   // 0..7 -> rows tr*4..tr*4+3
    int tc = tid & 31;   // 0..31 -> cols tc*4..tc*4+3
    float4 bias4 = ((const float4*)bias)[tc];
    float acc[4][4];
#pragma unroll
    for (int i = 0; i < 4; ++i) {
        acc[i][0] = bias4.x; acc[i][1] = bias4.y;
        acc[i][2] = bias4.z; acc[i][3] = bias4.w;
    }

    for (int ks = 0; ks < 4; ++ks) {
        __syncthreads();
        for (int i = tid; i < 32 * 128; i += 256)
            Ws[i] = W[ks * 32 * 128 + i];
        __syncthreads();
#pragma unroll
        for (int k = 0; k < 32; k += 4) {
            float4 a[4];
#pragma unroll
            for (int i = 0; i < 4; ++i)
                a[i] = *(const float4*)&As[tr * 4 + i][ks * 32 + k];
#pragma unroll
            for (int q = 0; q < 4; ++q) {
                float4 b = *(const float4*)&Ws[(k + q) * 128 + tc * 4];
#pragma unroll
                for (int i = 0; i < 4; ++i) {
                    float av = ((const float*)&a[i])[q];
                    acc[i][0] = fmaf(av, b.x, acc[i][0]);
                    acc[i][1] = fmaf(av, b.y, acc[i][1]);
                    acc[i][2] = fmaf(av, b.z, acc[i][2]);
                    acc[i][3] = fmaf(av, b.w, acc[i][3]);
                }
            }
        }
    }

#pragma unroll
    for (int i = 0; i < 4; ++i) {
        float4 v = make_float4(acc[i][0], acc[i][1], acc[i][2], acc[i][3]);
        if (relu_flag) {
            v.x = fmaxf(v.x, 0.f); v.y = fmaxf(v.y, 0.f);
            v.z = fmaxf(v.z, 0.f); v.w = fmaxf(v.w, 0.f);
        }
        ((float4*)&C[(row0 + tr * 4 + i) * F])[tc] = v;
    }
}

// ---------------- combined = h0 + h1 + h2 (vectorized) ---------------------
__global__ void combine_kernel(const float4* __restrict__ h0,
                               const float4* __restrict__ h1,
                               const float4* __restrict__ h2,
                               float4* __restrict__ out) {
    int i = blockIdx.x * blockDim.x + threadIdx.x;
    if (i >= NF / 4) return;
    float4 a = h0[i], b = h1[i], c = h2[i];
    out[i] = make_float4(a.x + b.x + c.x, a.y + b.y + c.y,
                         a.z + b.z + c.z, a.w + b.w + c.w);
}

extern "C" void kernel_launch(void* const* d_in, const int* in_sizes, int n_in,
                              void* d_out, int out_size, void* d_ws, size_t ws_size,
                              hipStream_t stream) {
    const float* feat = (const float*)d_in[0];
    const int* src[3] = {(const int*)d_in[1], (const int*)d_in[3], (const int*)d_in[5]};
    const int* dst[3] = {(const int*)d_in[2], (const int*)d_in[4], (const int*)d_in[6]};
    const float* We[3] = {(const float*)d_in[7], (const float*)d_in[9], (const float*)d_in[11]};
    const float* be[3] = {(const float*)d_in[8], (const float*)d_in[10], (const float*)d_in[12]};
    const float* Wr1 = (const float*)d_in[13];
    const float* br1 = (const float*)d_in[14];
    const float* Wr2 = (const float*)d_in[15];
    const float* br2 = (const float*)d_in[16];

    float* out = (float*)d_out;
    float* rec = out;                 // [N,128] final reconstructed
    float* h[3] = {out + NF, out + 2 * NF, out + 3 * NF};

    // workspace layout
    int*   out_cnt = (int*)d_ws;            // 3N ints
    int*   in_cnt  = out_cnt + 3 * NN;      // 3N ints
    float* rs      = (float*)(in_cnt + 3 * NN); // 3N floats
    int*   slots   = (int*)(rs + 3 * NN);   // N*SLOT_CAP ints (reused per etype)

    hipMemsetAsync(out_cnt, 0, (size_t)6 * NN * sizeof(int), stream);

    dim3 gE((EE + 255) / 256, 3);
    count_out_kernel<<<gE, 256, 0, stream>>>(src[0], src[1], src[2], out_cnt);
    rs_out_kernel<<<(3 * NN + 255) / 256, 256, 0, stream>>>(out_cnt, rs);

    for (int e = 0; e < 3; ++e) {
        fill_kernel<<<(EE + 255) / 256, 256, 0, stream>>>(src[e], dst[e],
                                                          in_cnt + e * NN, slots);
        gather_kernel<<<NN / 2, 256, 0, stream>>>(feat, slots, in_cnt + e * NN,
                                                  rs + e * NN, h[e]);
        matmul_kernel<<<NN / 32, 256, 0, stream>>>(h[e], We[e], be[e], h[e], 1);
    }

    combine_kernel<<<(NF / 4 + 255) / 256, 256, 0, stream>>>(
        (const float4*)h[0], (const float4*)h[1], (const float4*)h[2], (float4*)rec);

    matmul_kernel<<<NN / 32, 256, 0, stream>>>(rec, Wr1, br1, rec, 1);
    matmul_kernel<<<NN / 32, 256, 0, stream>>>(rec, Wr2, br2, rec, 0);
}

// Round 2
// 941.296 us; speedup vs baseline: 1.2495x; 1.2495x over previous
//
#include <hip/hip_runtime.h>

#define NN 100000      // nodes
#define EE 600000      // edges per etype
#define F  128         // IN == H == 128
#define NF (NN * F)
#define SLOT_CAP 64

// ---------------- degree counting (out-degree over src, all 3 etypes) ------
__global__ void count_out_kernel(const int* __restrict__ src0,
                                 const int* __restrict__ src1,
                                 const int* __restrict__ src2,
                                 int* __restrict__ out_cnt) {
    int i = blockIdx.x * blockDim.x + threadIdx.x;
    if (i >= EE) return;
    int e = blockIdx.y;
    const int* s = (e == 0) ? src0 : (e == 1) ? src1 : src2;
    atomicAdd(&out_cnt[e * NN + s[i]], 1);
}

__global__ void rs_out_kernel(const int* __restrict__ cnt, float* __restrict__ rs) {
    int i = blockIdx.x * blockDim.x + threadIdx.x;
    if (i >= 3 * NN) return;
    int c = cnt[i];
    if (c < 1) c = 1;
    rs[i] = rsqrtf((float)c);
}

// ---------------- bucket edges by dst (builds per-node src list) -----------
__global__ void fill_kernel(const int* __restrict__ src, const int* __restrict__ dst,
                            int* __restrict__ in_cnt, int* __restrict__ slots) {
    int i = blockIdx.x * blockDim.x + threadIdx.x;
    if (i >= EE) return;
    int d = dst[i];
    int p = atomicAdd(&in_cnt[d], 1);
    if (p < SLOT_CAP) slots[d * SLOT_CAP + p] = src[i];
}

// ---------------- atomic-free gather SpMM with both norms ------------------
// 32 threads/node, float4 per lane (16B), 2 edges in flight per iteration.
// agg[d] = rsqrt(in_deg[d]) * sum_{s in N(d)} feat[s] * rsqrt(out_deg[s])
__global__ __launch_bounds__(256) void gather_kernel(
        const float* __restrict__ feat,
        const int* __restrict__ slots,
        const int* __restrict__ in_cnt,
        const float* __restrict__ rs_out,
        float* __restrict__ agg) {
    int node = blockIdx.x * 8 + (threadIdx.x >> 5);
    int c4 = threadIdx.x & 31;        // float4 index within 128-wide row
    if (node >= NN) return;
    int cnt = in_cnt[node];
    int lim = cnt < SLOT_CAP ? cnt : SLOT_CAP;
    const int* sl = slots + node * SLOT_CAP;
    const float4* f4 = (const float4*)feat;
    float4 acc0 = make_float4(0.f, 0.f, 0.f, 0.f);
    float4 acc1 = make_float4(0.f, 0.f, 0.f, 0.f);
    int j = 0;
    for (; j + 2 <= lim; j += 2) {
        int s0 = sl[j], s1 = sl[j + 1];
        float r0 = rs_out[s0], r1 = rs_out[s1];
        float4 v0 = f4[s0 * 32 + c4];
        float4 v1 = f4[s1 * 32 + c4];
        acc0.x = fmaf(v0.x, r0, acc0.x); acc0.y = fmaf(v0.y, r0, acc0.y);
        acc0.z = fmaf(v0.z, r0, acc0.z); acc0.w = fmaf(v0.w, r0, acc0.w);
        acc1.x = fmaf(v1.x, r1, acc1.x); acc1.y = fmaf(v1.y, r1, acc1.y);
        acc1.z = fmaf(v1.z, r1, acc1.z); acc1.w = fmaf(v1.w, r1, acc1.w);
    }
    if (j < lim) {
        int s0 = sl[j];
        float r0 = rs_out[s0];
        float4 v0 = f4[s0 * 32 + c4];
        acc0.x = fmaf(v0.x, r0, acc0.x); acc0.y = fmaf(v0.y, r0, acc0.y);
        acc0.z = fmaf(v0.z, r0, acc0.z); acc0.w = fmaf(v0.w, r0, acc0.w);
    }
    float rin = rsqrtf((float)(cnt < 1 ? 1 : cnt));
    float4 r = make_float4((acc0.x + acc1.x) * rin, (acc0.y + acc1.y) * rin,
                           (acc0.z + acc1.z) * rin, (acc0.w + acc1.w) * rin);
    ((float4*)agg)[node * 32 + c4] = r;
}

// ---------------- fp32 matmul: C[r] = act(sum_i A_i[r] @ W + bias) ---------
// 32 rows / block, 256 threads: tr=tid>>5 (4 rows each), tc=tid&31 (4 cols).
// A staged in LDS (optionally summing 3 sources); W staged in 32-k chunks.
// In-place safe (block writes exactly the rows it staged).
__global__ __launch_bounds__(256) void matmul_kernel(
        const float* __restrict__ A, const float* __restrict__ A1,
        const float* __restrict__ A2, const float* __restrict__ W,
        const float* __restrict__ bias, float* __restrict__ C, int relu_flag) {
    __shared__ __align__(16) float As[32][132];
    __shared__ __align__(16) float Ws[32 * 128];
    int tid = threadIdx.x;
    int row0 = blockIdx.x * 32;

    // stage A rows: coalesced float4 global reads (sum 3 sources if fused)
    for (int i = tid; i < 32 * 32; i += 256) {
        int r = i >> 5, kq = (i & 31) * 4;
        int off = (row0 + r) * F + kq;
        float4 v = *(const float4*)&A[off];
        if (A1) {
            float4 u = *(const float4*)&A1[off];
            float4 w = *(const float4*)&A2[off];
            v.x += u.x + w.x; v.y += u.y + w.y;
            v.z += u.z + w.z; v.w += u.w + w.w;
        }
        *(float4*)&As[r][kq] = v;
    }

    int tr = tid >> 5;   // 0..7 -> rows tr*4..tr*4+3
    int tc = tid & 31;   // 0..31 -> cols tc*4..tc*4+3
    float4 bias4 = ((const float4*)bias)[tc];
    float acc[4][4];
#pragma unroll
    for (int i = 0; i < 4; ++i) {
        acc[i][0] = bias4.x; acc[i][1] = bias4.y;
        acc[i][2] = bias4.z; acc[i][3] = bias4.w;
    }

    for (int ks = 0; ks < 4; ++ks) {
        __syncthreads();
        for (int i = tid; i < 32 * 128; i += 256)
            Ws[i] = W[ks * 32 * 128 + i];
        __syncthreads();
#pragma unroll
        for (int k = 0; k < 32; k += 4) {
            float4 a[4];
#pragma unroll
            for (int i = 0; i < 4; ++i)
                a[i] = *(const float4*)&As[tr * 4 + i][ks * 32 + k];
#pragma unroll
            for (int q = 0; q < 4; ++q) {
                float4 b = *(const float4*)&Ws[(k + q) * 128 + tc * 4];
#pragma unroll
                for (int i = 0; i < 4; ++i) {
                    float av = ((const float*)&a[i])[q];
                    acc[i][0] = fmaf(av, b.x, acc[i][0]);
                    acc[i][1] = fmaf(av, b.y, acc[i][1]);
                    acc[i][2] = fmaf(av, b.z, acc[i][2]);
                    acc[i][3] = fmaf(av, b.w, acc[i][3]);
                }
            }
        }
    }

#pragma unroll
    for (int i = 0; i < 4; ++i) {
        float4 v = make_float4(acc[i][0], acc[i][1], acc[i][2], acc[i][3]);
        if (relu_flag) {
            v.x = fmaxf(v.x, 0.f); v.y = fmaxf(v.y, 0.f);
            v.z = fmaxf(v.z, 0.f); v.w = fmaxf(v.w, 0.f);
        }
        ((float4*)&C[(row0 + tr * 4 + i) * F])[tc] = v;
    }
}

extern "C" void kernel_launch(void* const* d_in, const int* in_sizes, int n_in,
                              void* d_out, int out_size, void* d_ws, size_t ws_size,
                              hipStream_t stream) {
    const float* feat = (const float*)d_in[0];
    const int* src[3] = {(const int*)d_in[1], (const int*)d_in[3], (const int*)d_in[5]};
    const int* dst[3] = {(const int*)d_in[2], (const int*)d_in[4], (const int*)d_in[6]};
    const float* We[3] = {(const float*)d_in[7], (const float*)d_in[9], (const float*)d_in[11]};
    const float* be[3] = {(const float*)d_in[8], (const float*)d_in[10], (const float*)d_in[12]};
    const float* Wr1 = (const float*)d_in[13];
    const float* br1 = (const float*)d_in[14];
    const float* Wr2 = (const float*)d_in[15];
    const float* br2 = (const float*)d_in[16];

    float* out = (float*)d_out;
    float* rec = out;                 // [N,128] final reconstructed
    float* h[3] = {out + NF, out + 2 * NF, out + 3 * NF};

    // workspace layout
    int*   out_cnt = (int*)d_ws;            // 3N ints
    int*   in_cnt  = out_cnt + 3 * NN;      // 3N ints
    float* rs      = (float*)(in_cnt + 3 * NN); // 3N floats
    int*   slots   = (int*)(rs + 3 * NN);   // N*SLOT_CAP ints (reused per etype)

    hipMemsetAsync(out_cnt, 0, (size_t)6 * NN * sizeof(int), stream);

    dim3 gE((EE + 255) / 256, 3);
    count_out_kernel<<<gE, 256, 0, stream>>>(src[0], src[1], src[2], out_cnt);
    rs_out_kernel<<<(3 * NN + 255) / 256, 256, 0, stream>>>(out_cnt, rs);

    for (int e = 0; e < 3; ++e) {
        fill_kernel<<<(EE + 255) / 256, 256, 0, stream>>>(src[e], dst[e],
                                                          in_cnt + e * NN, slots);
        gather_kernel<<<(NN + 7) / 8, 256, 0, stream>>>(feat, slots, in_cnt + e * NN,
                                                        rs + e * NN, h[e]);
        matmul_kernel<<<NN / 32, 256, 0, stream>>>(h[e], nullptr, nullptr,
                                                   We[e], be[e], h[e], 1);
    }

    // fused: rec = relu((h0+h1+h2) @ Wr1 + br1)
    matmul_kernel<<<NN / 32, 256, 0, stream>>>(h[0], h[1], h[2], Wr1, br1, rec, 1);
    // rec = rec @ Wr2 + br2
    matmul_kernel<<<NN / 32, 256, 0, stream>>>(rec, nullptr, nullptr, Wr2, br2, rec, 0);
}

// Round 3
// 740.499 us; speedup vs baseline: 1.5884x; 1.2712x over previous
//
#include <hip/hip_runtime.h>

#define NN 100000      // nodes
#define EE 600000      // edges per etype
#define F  128         // IN == H == 128
#define NF (NN * F)
#define NPAD 100096    // 782 * 128 (row-padded for full 128-row tiles)
#define SLOT_CAP 64

typedef __attribute__((ext_vector_type(8))) short short8;
typedef __attribute__((ext_vector_type(4))) float floatx4;

__device__ inline unsigned short f2bf(float x) {
    union { float f; unsigned u; } v; v.f = x;
    unsigned r = v.u + 0x7FFF + ((v.u >> 16) & 1);   // RTN-even
    return (unsigned short)(r >> 16);
}

__device__ inline void gld_lds16(const void* g, void* l) {
    __builtin_amdgcn_global_load_lds(
        (const __attribute__((address_space(1))) void*)g,
        (__attribute__((address_space(3))) void*)l, 16, 0, 0);
}

// ---------------- weight prep: Wt[n][k] = bf16(W[k][n]), 5 weights --------
__global__ void prep_weights_kernel(const float* __restrict__ W0, const float* __restrict__ W1,
                                    const float* __restrict__ W2, const float* __restrict__ W3,
                                    const float* __restrict__ W4, unsigned short* __restrict__ Wt) {
    int w = blockIdx.y;
    const float* W = (w == 0) ? W0 : (w == 1) ? W1 : (w == 2) ? W2 : (w == 3) ? W3 : W4;
    int t = blockIdx.x * 256 + threadIdx.x;   // 0..16383
    int k = t >> 7, n = t & 127;
    Wt[w * F * F + n * F + k] = f2bf(W[t]);
}

// ---------------- fused edge pass: out-degree count + dst bucketing --------
__global__ void fill_count_kernel(const int* __restrict__ src0, const int* __restrict__ src1,
                                  const int* __restrict__ src2, const int* __restrict__ dst0,
                                  const int* __restrict__ dst1, const int* __restrict__ dst2,
                                  int* __restrict__ out_cnt, int* __restrict__ in_cnt,
                                  int* __restrict__ slots) {
    int i = blockIdx.x * blockDim.x + threadIdx.x;
    if (i >= EE) return;
    int e = blockIdx.y;
    const int* sp = (e == 0) ? src0 : (e == 1) ? src1 : src2;
    const int* dp = (e == 0) ? dst0 : (e == 1) ? dst1 : dst2;
    int s = sp[i], d = dp[i];
    atomicAdd(&out_cnt[e * NN + s], 1);
    int p = atomicAdd(&in_cnt[e * NN + d], 1);
    if (p < SLOT_CAP) slots[(size_t)e * NN * SLOT_CAP + (size_t)d * SLOT_CAP + p] = s;
}

__global__ void rs_out_kernel(const int* __restrict__ cnt, float* __restrict__ rs) {
    int i = blockIdx.x * blockDim.x + threadIdx.x;
    if (i >= 3 * NN) return;
    int c = cnt[i];
    if (c < 1) c = 1;
    rs[i] = rsqrtf((float)c);
}

// ---------------- atomic-free gather SpMM, bf16 output ---------------------
// agg[d] = bf16( rsqrt(in_deg[d]) * sum_{s in N(d)} feat[s] * rsqrt(out_deg[s]) )
__global__ __launch_bounds__(256) void gather_kernel(
        const float* __restrict__ feat,
        const int* __restrict__ slots,      // base, indexed by etype
        const int* __restrict__ in_cnt,
        const float* __restrict__ rs_out,
        unsigned short* __restrict__ agg) {
    int e = blockIdx.y;
    int node = blockIdx.x * 8 + (threadIdx.x >> 5);
    int c4 = threadIdx.x & 31;        // float4 index within 128-wide row
    if (node >= NN) return;
    int cnt = in_cnt[e * NN + node];
    int lim = cnt < SLOT_CAP ? cnt : SLOT_CAP;
    const int* sl = slots + (size_t)e * NN * SLOT_CAP + (size_t)node * SLOT_CAP;
    const float* rs = rs_out + e * NN;
    const float4* f4 = (const float4*)feat;
    float4 acc0 = make_float4(0.f, 0.f, 0.f, 0.f);
    float4 acc1 = make_float4(0.f, 0.f, 0.f, 0.f);
    int j = 0;
    for (; j + 2 <= lim; j += 2) {
        int s0 = sl[j], s1 = sl[j + 1];
        float r0 = rs[s0], r1 = rs[s1];
        float4 v0 = f4[s0 * 32 + c4];
        float4 v1 = f4[s1 * 32 + c4];
        acc0.x = fmaf(v0.x, r0, acc0.x); acc0.y = fmaf(v0.y, r0, acc0.y);
        acc0.z = fmaf(v0.z, r0, acc0.z); acc0.w = fmaf(v0.w, r0, acc0.w);
        acc1.x = fmaf(v1.x, r1, acc1.x); acc1.y = fmaf(v1.y, r1, acc1.y);
        acc1.z = fmaf(v1.z, r1, acc1.z); acc1.w = fmaf(v1.w, r1, acc1.w);
    }
    if (j < lim) {
        int s0 = sl[j];
        float r0 = rs[s0];
        float4 v0 = f4[s0 * 32 + c4];
        acc0.x = fmaf(v0.x, r0, acc0.x); acc0.y = fmaf(v0.y, r0, acc0.y);
        acc0.z = fmaf(v0.z, r0, acc0.z); acc0.w = fmaf(v0.w, r0, acc0.w);
    }
    float rin = rsqrtf((float)(cnt < 1 ? 1 : cnt));
    ushort4 r;
    r.x = f2bf((acc0.x + acc1.x) * rin);
    r.y = f2bf((acc0.y + acc1.y) * rin);
    r.z = f2bf((acc0.z + acc1.z) * rin);
    r.w = f2bf((acc0.w + acc1.w) * rin);
    *(ushort4*)&agg[(size_t)e * NPAD * F + (size_t)node * F + c4 * 4] = r;
}

// ---------------- MFMA matmul: C = act((A or A0+A1+A2) @ W + bias) ---------
// 128x128 block tile, 256 thr = 4 waves in 2x2, each wave 64x64 via 16
// mfma_f32_16x16x32_bf16 tiles. Whole K=128 and whole W^T in LDS (64KB).
// A path 1: Abf bf16 row-padded -> global_load_lds 16B staging.
// A path 2: Abf==null -> stage sum of up to 3 fp32 sources, convert to bf16.
// Wt is [n][k] bf16 (pre-transposed) so A/B frags load identically (m97 B^T).
__global__ __launch_bounds__(256) void mfma_matmul_kernel(
        const unsigned short* __restrict__ Abf,
        const float* __restrict__ A0, const float* __restrict__ A1,
        const float* __restrict__ A2,
        const unsigned short* __restrict__ Wt,
        const float* __restrict__ bias,
        float* __restrict__ C, unsigned short* __restrict__ Cbf,
        int relu_flag) {
    __shared__ unsigned short Abuf[F * F];   // 32KB
    __shared__ unsigned short Wbuf[F * F];   // 32KB
    int tid = threadIdx.x;
    int lane = tid & 63, wv = tid >> 6;
    int row0 = blockIdx.x * F;

    // stage W^T (bf16, contiguous 32KB)
    for (int i = 0; i < 8; ++i)
        gld_lds16(Wt + i * 2048 + wv * 512 + lane * 8, Wbuf + i * 2048 + wv * 512);

    if (Abf) {
        const unsigned short* Asrc = Abf + (size_t)row0 * F;
        for (int i = 0; i < 8; ++i)
            gld_lds16(Asrc + i * 2048 + wv * 512 + lane * 8, Abuf + i * 2048 + wv * 512);
    } else {
        for (int i = 0; i < 8; ++i) {
            int e = (i * 256 + tid) * 8;      // element in 128x128 tile
            int r = e >> 7, c = e & 127;
            int grow = row0 + r;
            float4 u0 = make_float4(0.f, 0.f, 0.f, 0.f), u1 = u0;
            if (grow < NN) {
                size_t off = (size_t)grow * F + c;
                u0 = *(const float4*)(A0 + off);
                u1 = *(const float4*)(A0 + off + 4);
                if (A1) {
                    float4 a = *(const float4*)(A1 + off), b = *(const float4*)(A1 + off + 4);
                    float4 p = *(const float4*)(A2 + off), q = *(const float4*)(A2 + off + 4);
                    u0.x += a.x + p.x; u0.y += a.y + p.y; u0.z += a.z + p.z; u0.w += a.w + p.w;
                    u1.x += b.x + q.x; u1.y += b.y + q.y; u1.z += b.z + q.z; u1.w += b.w + q.w;
                }
            }
            short8 s;
            s[0] = (short)f2bf(u0.x); s[1] = (short)f2bf(u0.y);
            s[2] = (short)f2bf(u0.z); s[3] = (short)f2bf(u0.w);
            s[4] = (short)f2bf(u1.x); s[5] = (short)f2bf(u1.y);
            s[6] = (short)f2bf(u1.z); s[7] = (short)f2bf(u1.w);
            *(short8*)&Abuf[r * F + c] = s;
        }
    }
    __syncthreads();   // drains vmcnt (global_load_lds) + lgkm

    int wm = (wv >> 1) * 64, wn = (wv & 1) * 64;
    int q = lane >> 4, mr = lane & 15;

    floatx4 acc[4][4];
#pragma unroll
    for (int mi = 0; mi < 4; ++mi)
#pragma unroll
        for (int ni = 0; ni < 4; ++ni)
            acc[mi][ni] = (floatx4){0.f, 0.f, 0.f, 0.f};

#pragma unroll
    for (int k0 = 0; k0 < 128; k0 += 32) {
        short8 af[4], bfv[4];
#pragma unroll
        for (int t = 0; t < 4; ++t)
            af[t] = *(const short8*)&Abuf[(wm + t * 16 + mr) * F + k0 + q * 8];
#pragma unroll
        for (int t = 0; t < 4; ++t)
            bfv[t] = *(const short8*)&Wbuf[(wn + t * 16 + mr) * F + k0 + q * 8];
#pragma unroll
        for (int mi = 0; mi < 4; ++mi)
#pragma unroll
            for (int ni = 0; ni < 4; ++ni)
                acc[mi][ni] = __builtin_amdgcn_mfma_f32_16x16x32_bf16(
                    af[mi], bfv[ni], acc[mi][ni], 0, 0, 0);
    }

    // epilogue: C/D layout col=lane&15, row=quad*4+reg (m89/m91-verified)
#pragma unroll
    for (int ni = 0; ni < 4; ++ni) {
        int col = wn + ni * 16 + mr;
        float bv = bias[col];
#pragma unroll
        for (int mi = 0; mi < 4; ++mi) {
#pragma unroll
            for (int r = 0; r < 4; ++r) {
                int grow = row0 + wm + mi * 16 + q * 4 + r;
                if (grow < NN) {
                    float v = acc[mi][ni][r] + bv;
                    if (relu_flag) v = fmaxf(v, 0.f);
                    C[(size_t)grow * F + col] = v;
                    if (Cbf) Cbf[(size_t)grow * F + col] = f2bf(v);
                }
            }
        }
    }
}

extern "C" void kernel_launch(void* const* d_in, const int* in_sizes, int n_in,
                              void* d_out, int out_size, void* d_ws, size_t ws_size,
                              hipStream_t stream) {
    const float* feat = (const float*)d_in[0];
    const int* src[3] = {(const int*)d_in[1], (const int*)d_in[3], (const int*)d_in[5]};
    const int* dst[3] = {(const int*)d_in[2], (const int*)d_in[4], (const int*)d_in[6]};
    const float* We[3] = {(const float*)d_in[7], (const float*)d_in[9], (const float*)d_in[11]};
    const float* be[3] = {(const float*)d_in[8], (const float*)d_in[10], (const float*)d_in[12]};
    const float* Wr1 = (const float*)d_in[13];
    const float* br1 = (const float*)d_in[14];
    const float* Wr2 = (const float*)d_in[15];
    const float* br2 = (const float*)d_in[16];

    float* out = (float*)d_out;
    float* rec = out;                 // [N,128] final reconstructed
    float* h[3] = {out + NF, out + 2 * NF, out + 3 * NF};

    // workspace layout
    int* out_cnt = (int*)d_ws;                              // 3N
    int* in_cnt  = out_cnt + 3 * NN;                        // 3N
    float* rs    = (float*)(in_cnt + 3 * NN);               // 3N
    unsigned short* Wt   = (unsigned short*)(rs + 3 * NN);  // 5*128*128 bf16
    unsigned short* agg  = Wt + 5 * F * F;                  // 3*NPAD*128 bf16
    unsigned short* recbf = agg + (size_t)3 * NPAD * F;     // NPAD*128 bf16
    int* slots = (int*)(recbf + (size_t)NPAD * F);          // 3*N*64

    hipMemsetAsync(out_cnt, 0, (size_t)6 * NN * sizeof(int), stream);

    prep_weights_kernel<<<dim3(64, 5), 256, 0, stream>>>(We[0], We[1], We[2], Wr1, Wr2, Wt);

    fill_count_kernel<<<dim3((EE + 255) / 256, 3), 256, 0, stream>>>(
        src[0], src[1], src[2], dst[0], dst[1], dst[2], out_cnt, in_cnt, slots);

    rs_out_kernel<<<(3 * NN + 255) / 256, 256, 0, stream>>>(out_cnt, rs);

    gather_kernel<<<dim3((NN + 7) / 8, 3), 256, 0, stream>>>(feat, slots, in_cnt, rs, agg);

    int mm_grid = NPAD / F;  // 782
    for (int e = 0; e < 3; ++e)
        mfma_matmul_kernel<<<mm_grid, 256, 0, stream>>>(
            agg + (size_t)e * NPAD * F, nullptr, nullptr, nullptr,
            Wt + e * F * F, be[e], h[e], nullptr, 1);

    // rec = relu((h0+h1+h2) @ Wr1 + br1), dual-write bf16 copy
    mfma_matmul_kernel<<<mm_grid, 256, 0, stream>>>(
        nullptr, h[0], h[1], h[2], Wt + 3 * F * F, br1, rec, recbf, 1);
    // rec = recbf @ Wr2 + br2
    mfma_matmul_kernel<<<mm_grid, 256, 0, stream>>>(
        recbf, nullptr, nullptr, nullptr, Wt + 4 * F * F, br2, rec, nullptr, 0);
}

// Round 4
// 626.486 us; speedup vs baseline: 1.8774x; 1.1820x over previous
//
#include <hip/hip_runtime.h>

#define NN 100000      // nodes
#define EE 600000      // edges per etype
#define F  128         // IN == H == 128
#define NF (NN * F)
#define NPAD 100096    // 782 * 128 (row-padded for full 128-row tiles)
#define SLOT_CAP 32    // P(in_deg > 32 | Poisson(6)) ~ 1e-16 — safe

typedef __attribute__((ext_vector_type(8))) short short8;
typedef __attribute__((ext_vector_type(4))) float floatx4;

__device__ inline unsigned short f2bf(float x) {
    union { float f; unsigned u; } v; v.f = x;
    unsigned r = v.u + 0x7FFF + ((v.u >> 16) & 1);   // RTN-even
    return (unsigned short)(r >> 16);
}
__device__ inline float bf2f(unsigned short b) {
    union { unsigned u; float f; } v; v.u = ((unsigned)b) << 16;
    return v.f;
}

__device__ inline void gld_lds16(const void* g, void* l) {
    __builtin_amdgcn_global_load_lds(
        (const __attribute__((address_space(1))) void*)g,
        (__attribute__((address_space(3))) void*)l, 16, 0, 0);
}

// ---------------- weight prep: Wt[n][k] = bf16(W[k][n]), 5 weights ---------
__global__ void prep_weights_kernel(const float* __restrict__ W0, const float* __restrict__ W1,
                                    const float* __restrict__ W2, const float* __restrict__ W3,
                                    const float* __restrict__ W4, unsigned short* __restrict__ Wt) {
    int w = blockIdx.y;
    const float* W = (w == 0) ? W0 : (w == 1) ? W1 : (w == 2) ? W2 : (w == 3) ? W3 : W4;
    int t = blockIdx.x * 256 + threadIdx.x;   // 0..16383
    int k = t >> 7, n = t & 127;
    Wt[w * F * F + n * F + k] = f2bf(W[t]);
}

// ---------------- feat fp32 -> bf16 (row-padded) ---------------------------
__global__ void featbf_kernel(const float* __restrict__ feat, unsigned short* __restrict__ fb) {
    int t = blockIdx.x * 256 + threadIdx.x;   // one float4 -> ushort4
    if (t >= NF / 4) return;
    float4 v = ((const float4*)feat)[t];
    ushort4 r;
    r.x = f2bf(v.x); r.y = f2bf(v.y); r.z = f2bf(v.z); r.w = f2bf(v.w);
    ((ushort4*)fb)[t] = r;
}

// ---------------- fused edge pass: out-deg count + dst bucketing -----------
// p-major slot layout: slots[(e*CAP+p)*NN + d] — dense 400KB planes so the
// random 4B scatter writes re-hit L2-resident lines (kills the 64B-line
// write amplification that made this kernel 176us).
__global__ void fill_count_kernel(const int* __restrict__ src0, const int* __restrict__ src1,
                                  const int* __restrict__ src2, const int* __restrict__ dst0,
                                  const int* __restrict__ dst1, const int* __restrict__ dst2,
                                  int* __restrict__ out_cnt, int* __restrict__ in_cnt,
                                  int* __restrict__ slots) {
    int i = blockIdx.x * blockDim.x + threadIdx.x;
    if (i >= EE) return;
    int e = blockIdx.y;
    const int* sp = (e == 0) ? src0 : (e == 1) ? src1 : src2;
    const int* dp = (e == 0) ? dst0 : (e == 1) ? dst1 : dst2;
    int s = sp[i], d = dp[i];
    atomicAdd(&out_cnt[e * NN + s], 1);
    int p = atomicAdd(&in_cnt[e * NN + d], 1);
    if (p < SLOT_CAP) slots[(size_t)(e * SLOT_CAP + p) * NN + d] = s;
}

__global__ void rs_out_kernel(const int* __restrict__ cnt, float* __restrict__ rs) {
    int i = blockIdx.x * blockDim.x + threadIdx.x;
    if (i >= 3 * NN) return;
    int c = cnt[i];
    if (c < 1) c = 1;
    rs[i] = rsqrtf((float)c);
}

// ---------------- MFMA matmul: C = act(A @ W + bias), bf16 A ---------------
// 128x128 block tile, 4 waves 2x2, mfma_f32_16x16x32_bf16, K=128 in LDS.
__global__ __launch_bounds__(256) void mfma_matmul_kernel(
        const unsigned short* __restrict__ Abf,
        const unsigned short* __restrict__ WtBase,
        const float* __restrict__ bias,            // null -> 0
        float* __restrict__ C,                     // null -> skip fp32 store
        unsigned short* __restrict__ CbfBase,      // null -> skip bf16 store
        int relu_flag, size_t cbf_stride_rows) {
    __shared__ unsigned short Abuf[F * F];   // 32KB
    __shared__ unsigned short Wbuf[F * F];   // 32KB
    int tid = threadIdx.x;
    int lane = tid & 63, wv = tid >> 6;
    int row0 = blockIdx.x * F;
    const unsigned short* Wt = WtBase + (size_t)blockIdx.y * F * F;
    unsigned short* Cbf = CbfBase ? CbfBase + (size_t)blockIdx.y * cbf_stride_rows * F : nullptr;

    for (int i = 0; i < 8; ++i)
        gld_lds16(Wt + i * 2048 + wv * 512 + lane * 8, Wbuf + i * 2048 + wv * 512);
    const unsigned short* Asrc = Abf + (size_t)row0 * F;
    for (int i = 0; i < 8; ++i)
        gld_lds16(Asrc + i * 2048 + wv * 512 + lane * 8, Abuf + i * 2048 + wv * 512);
    __syncthreads();

    int wm = (wv >> 1) * 64, wn = (wv & 1) * 64;
    int q = lane >> 4, mr = lane & 15;

    floatx4 acc[4][4];
#pragma unroll
    for (int mi = 0; mi < 4; ++mi)
#pragma unroll
        for (int ni = 0; ni < 4; ++ni)
            acc[mi][ni] = (floatx4){0.f, 0.f, 0.f, 0.f};

#pragma unroll
    for (int k0 = 0; k0 < 128; k0 += 32) {
        short8 af[4], bfv[4];
#pragma unroll
        for (int t = 0; t < 4; ++t)
            af[t] = *(const short8*)&Abuf[(wm + t * 16 + mr) * F + k0 + q * 8];
#pragma unroll
        for (int t = 0; t < 4; ++t)
            bfv[t] = *(const short8*)&Wbuf[(wn + t * 16 + mr) * F + k0 + q * 8];
#pragma unroll
        for (int mi = 0; mi < 4; ++mi)
#pragma unroll
            for (int ni = 0; ni < 4; ++ni)
                acc[mi][ni] = __builtin_amdgcn_mfma_f32_16x16x32_bf16(
                    af[mi], bfv[ni], acc[mi][ni], 0, 0, 0);
    }

    // epilogue: C/D layout col=lane&15, row=quad*4+reg
#pragma unroll
    for (int ni = 0; ni < 4; ++ni) {
        int col = wn + ni * 16 + mr;
        float bv = bias ? bias[col] : 0.f;
#pragma unroll
        for (int mi = 0; mi < 4; ++mi) {
#pragma unroll
            for (int r = 0; r < 4; ++r) {
                int grow = row0 + wm + mi * 16 + q * 4 + r;
                float v = acc[mi][ni][r] + bv;
                if (relu_flag) v = fmaxf(v, 0.f);
                if (C && grow < NN) C[(size_t)grow * F + col] = v;
                if (Cbf) Cbf[(size_t)grow * F + col] = f2bf(v);
            }
        }
    }
}

// ---------------- gather: all 3 etypes per node, bf16 hpre rows ------------
// h_e[d] = relu( rs_in * sum_s rs_out[s]*hpre_e[s] + be_e ), hsum = bf16(sum_e pre-relu? NO:
// hsum = bf16(h0+h1+h2) (post-relu sum, matches reference combined)
// 32 lanes/node (4 cols each), 8 nodes/block.
__global__ __launch_bounds__(256) void gather_kernel(
        const unsigned short* __restrict__ hpre,
        const int* __restrict__ slots,
        const int* __restrict__ in_cnt,
        const float* __restrict__ rs_out,
        const float* __restrict__ be0, const float* __restrict__ be1,
        const float* __restrict__ be2,
        float* __restrict__ h0, float* __restrict__ h1, float* __restrict__ h2,
        unsigned short* __restrict__ hsum) {
    int node = blockIdx.x * 8 + (threadIdx.x >> 5);
    int l = threadIdx.x & 31;          // col group: cols l*4..l*4+3
    if (node >= NN) return;

    float hs[4] = {0.f, 0.f, 0.f, 0.f};
#pragma unroll
    for (int e = 0; e < 3; ++e) {
        int cnt = in_cnt[e * NN + node];
        int lim = cnt < SLOT_CAP ? cnt : SLOT_CAP;
        const int* sl = slots + (size_t)e * SLOT_CAP * NN + node;
        const float* rse = rs_out + e * NN;
        const unsigned short* hp = hpre + (size_t)e * NPAD * F;
        float a0[4] = {0.f, 0.f, 0.f, 0.f}, a1[4] = {0.f, 0.f, 0.f, 0.f};
        int p = 0;
        for (; p + 2 <= lim; p += 2) {
            int s0 = sl[(size_t)p * NN];
            int s1 = sl[(size_t)(p + 1) * NN];
            float r0 = rse[s0], r1 = rse[s1];
            ushort4 v0 = *(const ushort4*)&hp[(size_t)s0 * F + l * 4];
            ushort4 v1 = *(const ushort4*)&hp[(size_t)s1 * F + l * 4];
            a0[0] = fmaf(bf2f(v0.x), r0, a0[0]); a0[1] = fmaf(bf2f(v0.y), r0, a0[1]);
            a0[2] = fmaf(bf2f(v0.z), r0, a0[2]); a0[3] = fmaf(bf2f(v0.w), r0, a0[3]);
            a1[0] = fmaf(bf2f(v1.x), r1, a1[0]); a1[1] = fmaf(bf2f(v1.y), r1, a1[1]);
            a1[2] = fmaf(bf2f(v1.z), r1, a1[2]); a1[3] = fmaf(bf2f(v1.w), r1, a1[3]);
        }
        if (p < lim) {
            int s0 = sl[(size_t)p * NN];
            float r0 = rse[s0];
            ushort4 v0 = *(const ushort4*)&hp[(size_t)s0 * F + l * 4];
            a0[0] = fmaf(bf2f(v0.x), r0, a0[0]); a0[1] = fmaf(bf2f(v0.y), r0, a0[1]);
            a0[2] = fmaf(bf2f(v0.z), r0, a0[2]); a0[3] = fmaf(bf2f(v0.w), r0, a0[3]);
        }
        float rin = rsqrtf((float)(cnt < 1 ? 1 : cnt));
        const float* be = (e == 0) ? be0 : (e == 1) ? be1 : be2;
        float4 bv = *(const float4*)&be[l * 4];
        float4 hv;
        hv.x = fmaxf(fmaf(a0[0] + a1[0], rin, bv.x), 0.f);
        hv.y = fmaxf(fmaf(a0[1] + a1[1], rin, bv.y), 0.f);
        hv.z = fmaxf(fmaf(a0[2] + a1[2], rin, bv.z), 0.f);
        hv.w = fmaxf(fmaf(a0[3] + a1[3], rin, bv.w), 0.f);
        float* h = (e == 0) ? h0 : (e == 1) ? h1 : h2;
        *(float4*)&h[(size_t)node * F + l * 4] = hv;
        hs[0] += hv.x; hs[1] += hv.y; hs[2] += hv.z; hs[3] += hv.w;
    }
    ushort4 o;
    o.x = f2bf(hs[0]); o.y = f2bf(hs[1]); o.z = f2bf(hs[2]); o.w = f2bf(hs[3]);
    *(ushort4*)&hsum[(size_t)node * F + l * 4] = o;
}

extern "C" void kernel_launch(void* const* d_in, const int* in_sizes, int n_in,
                              void* d_out, int out_size, void* d_ws, size_t ws_size,
                              hipStream_t stream) {
    const float* feat = (const float*)d_in[0];
    const int* src[3] = {(const int*)d_in[1], (const int*)d_in[3], (const int*)d_in[5]};
    const int* dst[3] = {(const int*)d_in[2], (const int*)d_in[4], (const int*)d_in[6]};
    const float* We[3] = {(const float*)d_in[7], (const float*)d_in[9], (const float*)d_in[11]};
    const float* be[3] = {(const float*)d_in[8], (const float*)d_in[10], (const float*)d_in[12]};
    const float* Wr1 = (const float*)d_in[13];
    const float* br1 = (const float*)d_in[14];
    const float* Wr2 = (const float*)d_in[15];
    const float* br2 = (const float*)d_in[16];

    float* out = (float*)d_out;
    float* rec = out;                 // [N,128] final reconstructed
    float* h[3] = {out + NF, out + 2 * NF, out + 3 * NF};

    // workspace layout (~170 MB)
    int* out_cnt = (int*)d_ws;                               // 3N
    int* in_cnt  = out_cnt + 3 * NN;                         // 3N
    float* rs    = (float*)(in_cnt + 3 * NN);                // 3N
    unsigned short* Wt     = (unsigned short*)(rs + 3 * NN); // 5*128*128
    unsigned short* featbf = Wt + 5 * F * F;                 // NPAD*F (reused as recbf)
    unsigned short* recbf  = featbf;                         //   (featbf dead after hpre matmuls)
    unsigned short* hsumbf = featbf + (size_t)NPAD * F;      // NPAD*F
    unsigned short* hpre   = hsumbf + (size_t)NPAD * F;      // 3*NPAD*F
    int* slots = (int*)(hpre + (size_t)3 * NPAD * F);        // 3*CAP*N

    hipMemsetAsync(out_cnt, 0, (size_t)6 * NN * sizeof(int), stream);

    prep_weights_kernel<<<dim3(64, 5), 256, 0, stream>>>(We[0], We[1], We[2], Wr1, Wr2, Wt);
    featbf_kernel<<<(NF / 4 + 255) / 256, 256, 0, stream>>>(feat, featbf);

    fill_count_kernel<<<dim3((EE + 255) / 256, 3), 256, 0, stream>>>(
        src[0], src[1], src[2], dst[0], dst[1], dst[2], out_cnt, in_cnt, slots);
    rs_out_kernel<<<(3 * NN + 255) / 256, 256, 0, stream>>>(out_cnt, rs);

    int mm_grid = NPAD / F;  // 782
    // hpre_e = featbf @ We_e  (bf16 out, no bias/relu), one dispatch, 3 etypes
    mfma_matmul_kernel<<<dim3(mm_grid, 3), 256, 0, stream>>>(
        featbf, Wt, nullptr, nullptr, hpre, 0, (size_t)NPAD);

    // gather + norm + bias + relu -> h0,h1,h2 (fp32) + hsum (bf16)
    gather_kernel<<<(NN + 7) / 8, 256, 0, stream>>>(
        hpre, slots, in_cnt, rs, be[0], be[1], be[2], h[0], h[1], h[2], hsumbf);

    // rec = relu(hsum @ Wr1 + br1), dual-write bf16 (featbf region now dead)
    mfma_matmul_kernel<<<mm_grid, 256, 0, stream>>>(
        hsumbf, Wt + 3 * F * F, br1, rec, recbf, 1, 0);
    // rec = recbf @ Wr2 + br2
    mfma_matmul_kernel<<<mm_grid, 256, 0, stream>>>(
        recbf, Wt + 4 * F * F, br2, rec, nullptr, 0, 0);
}